// Round 13
// baseline (60693.652 us; speedup 1.0000x reference)
//
#include <hip/hip_runtime.h>
#include <hip/hip_bf16.h>

#define B_   64
#define T_   2048
#define F_   256
#define H_   512
#define GB   4                    // batch groups (16 rows each)
#define GG   8                    // gate-split WGs per group
#define NWG  (GB*GG)              // 32
#define PAYD 4096                 // payload dwords per group: 16 rows * 256 pairs

typedef __attribute__((ext_vector_type(8))) short bfrag;   // 8 bf16 (MFMA A/B)
typedef __attribute__((ext_vector_type(4))) int   int4v;
typedef __attribute__((ext_vector_type(4))) float f32x4;
typedef __attribute__((ext_vector_type(4))) float float4_t;

__device__ __forceinline__ float fsig(float x)  { return 1.0f / (1.0f + __expf(-x)); }
__device__ __forceinline__ float ftanh(float x) { return 2.0f / (1.0f + __expf(-2.0f * x)) - 1.0f; }
__device__ __forceinline__ short f2bf(float f) {
  __hip_bfloat16 h = __float2bfloat16(f);
  return __builtin_bit_cast(short, h);
}

// ---- coherence-point (sc0 sc1: bypass L1+L2, serviced at MALL) ----
__device__ __forceinline__ int gload4_cc(const void* p) {
  int r;
  asm volatile("global_load_dword %0, %1, off sc0 sc1" : "=v"(r) : "v"(p));
  return r;
}
__device__ __forceinline__ void gstore4_cc(void* p, int d) {
  asm volatile("global_store_dword %0, %1, off sc0 sc1" :: "v"(p), "v"(d));
}
__device__ __forceinline__ int gload_flag(const void* p) {
  int r;
  asm volatile("global_load_dword %0, %1, off sc0 sc1\n\ts_waitcnt vmcnt(0)"
               : "=v"(r) : "v"(p) : "memory");
  return r;
}
__device__ __forceinline__ void vm_drain() {
  asm volatile("s_waitcnt vmcnt(0)" ::: "memory");
  __builtin_amdgcn_sched_barrier(0);   // rule #18
}

// ---------------- init: h0 payload into buf0, flags = 0, rt flags = 0 ----------
__global__ void lstm_init(const float* __restrict__ z, int* __restrict__ pay,
                          int* __restrict__ flags, int* __restrict__ rtf) {
  int i = blockIdx.x * blockDim.x + threadIdx.x;     // 0..16383
  if (i < GB * 16) flags[i] = 0;
  if (i < 64) rtf[i] = 0;
  int g  = i >> 12;
  int p  = i & 4095;
  int j  = p >> 8;
  int pr = p & 255;
  int row = 16 * g + j;
  int lo = (int)((unsigned)(unsigned short)f2bf(z[(size_t)row * H_ + 2 * pr])
         | ((unsigned)(unsigned short)f2bf(z[(size_t)row * H_ + 2 * pr + 1]) << 16));
  pay[(size_t)g * PAYD + p] = lo;                    // parity-0 buffer
}

// ============ PROBE 1: MALL ping-pong, 8192 rounds (4x, top-5 visible) =======
// dur/8192 = 2x UC one-way latency + 2x poll-detect. Theory: ~8us/round -> ~65ms.
__global__ void e_rt(int* e) {
  const int wg = blockIdx.x;
  const int l  = threadIdx.x;
  (void)l;
  if (wg == 0) {
    for (int t = 1; t <= 8192; ++t) {
      if (threadIdx.x == 0) gstore4_cc(&e[0], t);
      int g = 0;
      while (gload_flag(&e[16]) < t) { if (++g > 100000) return; }   // per-round guard
    }
  } else {
    for (int t = 1; t <= 8192; ++t) {
      int g = 0;
      while (gload_flag(&e[0]) < t) { if (++g > 100000) return; }
      if (threadIdx.x == 0) gstore4_cc(&e[16], t);
    }
  }
}

// ============ PROBE 2: pure compute body, 16384 steps (8x), ZERO UC ==========
__global__ void __launch_bounds__(256, 1)
e_comp(const float* __restrict__ Wih, const float* __restrict__ Whh,
       const float* __restrict__ bih, const float* __restrict__ bhh,
       const float* __restrict__ Wlin, const float* __restrict__ blin) {
  __shared__ char smem[49152];
  const int wg  = blockIdx.x;
  const int k   = wg & 7;
  const int tid = threadIdx.x;
  const int wv  = tid >> 6;
  const int l16 = (tid & 63) & 15;
  const int qq  = (tid & 63) >> 4;
  const int swz = (l16 & 7) << 4;

  {
    const int oc = tid >> 3;
    const float* src = Wlin + (size_t)(32 * k + oc) * H_ + (tid & 7) * 64;
    char* dst = smem + 16384 + oc * 1024;
    #pragma unroll
    for (int i = 0; i < 8; ++i) {
      bfrag tmp;
      #pragma unroll
      for (int e = 0; e < 8; ++e) tmp[e] = f2bf(src[i * 8 + e]);
      *(int4v*)(dst + ((((tid & 7) * 128) + i * 16) ^ ((oc & 7) << 4))) =
          __builtin_bit_cast(int4v, tmp);
    }
  }
  bfrag WH[4][16]; float bs[4];
  #pragma unroll
  for (int q = 0; q < 4; ++q) {
    const int grow = q * H_ + k * 64 + wv * 16 + l16;
    #pragma unroll
    for (int kt = 0; kt < 16; ++kt) {
      const float* s = Whh + (size_t)grow * H_ + kt * 32 + qq * 8;
      bfrag w;
      #pragma unroll
      for (int e = 0; e < 8; ++e) w[e] = f2bf(s[e]);
      WH[q][kt] = w;
    }
    bs[q] = bih[grow] + bhh[grow];
  }
  const float blc = (wv < 2) ? blin[32 * k + 16 * wv + l16] : 0.f;
  float c4[4] = {0.f, 0.f, 0.f, 0.f};
  __syncthreads();

  for (int t = 0; t < 16384; ++t) {
    int pv[16];
    #pragma unroll
    for (int j = 0; j < 16; ++j) pv[j] = (int)((t * 2654435761u) ^ (j << 8) ^ tid);
    __syncthreads();
    #pragma unroll
    for (int j = 0; j < 16; ++j)
      *(int*)(smem + j * 1024 + ((tid * 4) ^ ((j & 7) << 4))) = pv[j];
    __syncthreads();
    f32x4 acc[4] = {{0,0,0,0},{0,0,0,0},{0,0,0,0},{0,0,0,0}};
    #pragma unroll
    for (int kt = 0; kt < 16; ++kt) {
      bfrag a = *(const bfrag*)(smem + l16 * 1024 + ((kt * 64 + qq * 16) ^ swz));
      #pragma unroll
      for (int q = 0; q < 4; ++q)
        acc[q] = __builtin_amdgcn_mfma_f32_16x16x32_bf16(a, WH[q][kt], acc[q], 0, 0, 0);
    }
    #pragma unroll
    for (int r = 0; r < 4; ++r) {
      float iv = fsig(acc[0][r] + bs[0]);
      float fv = fsig(acc[1][r] + bs[1]);
      float gv = ftanh(acc[2][r] + bs[2]);
      float ov = fsig(acc[3][r] + bs[3]);
      float cn = fv * c4[r] + iv * gv;
      c4[r] = cn;
      float hn = ov * ftanh(cn);
      asm volatile("" :: "v"(hn));            // rule #17: live, no DCE
    }
    if (wv < 2) {
      f32x4 oacc = {blc, blc, blc, blc};
      #pragma unroll
      for (int kt = 0; kt < 16; ++kt) {
        bfrag a  = *(const bfrag*)(smem + l16 * 1024 + ((kt * 64 + qq * 16) ^ swz));
        bfrag wl = *(const bfrag*)(smem + 16384 + (16 * wv + l16) * 1024 +
                                   ((kt * 64 + qq * 16) ^ swz));
        oacc = __builtin_amdgcn_mfma_f32_16x16x32_bf16(a, wl, oacc, 0, 0, 0);
      }
      asm volatile("" :: "v"(oacc[0]), "v"(oacc[1]), "v"(oacc[2]), "v"(oacc[3]));
    }
  }
}

// ---------------- persistent LSTM (R9 verbatim — best passing, production) ----
__global__ void __launch_bounds__(256, 1)
lstm_persist(const float* __restrict__ x,
             const float* __restrict__ Wih,  const float* __restrict__ Whh,
             const float* __restrict__ bih,  const float* __restrict__ bhh,
             const float* __restrict__ Wlin, const float* __restrict__ blin,
             float* __restrict__ out, int* __restrict__ pay,
             int* __restrict__ flags)
{
  __shared__ char smem[49152];

  const int wg  = blockIdx.x;
  const int b   = wg >> 3;
  const int k   = wg & 7;
  const int tid = threadIdx.x;
  const int wv  = tid >> 6;
  const int l   = tid & 63;
  const int l16 = l & 15;
  const int qq  = l >> 4;
  const int swz = (l16 & 7) << 4;
  const int m4  = qq << 2;

  {
    const int oc = tid >> 3;
    const float* src = Wlin + (size_t)(32 * k + oc) * H_ + (tid & 7) * 64;
    char* dst = smem + 16384 + oc * 1024;
    #pragma unroll
    for (int i = 0; i < 8; ++i) {
      bfrag tmp;
      #pragma unroll
      for (int e = 0; e < 8; ++e) tmp[e] = f2bf(src[i * 8 + e]);
      *(int4v*)(dst + ((((tid & 7) * 128) + i * 16) ^ ((oc & 7) << 4))) =
          __builtin_bit_cast(int4v, tmp);
    }
  }

  bfrag WH[4][16]; bfrag WI[4][8]; float bs[4];
  #pragma unroll
  for (int q = 0; q < 4; ++q) {
    const int grow = q * H_ + k * 64 + wv * 16 + l16;
    #pragma unroll
    for (int kt = 0; kt < 16; ++kt) {
      const float* s = Whh + (size_t)grow * H_ + kt * 32 + qq * 8;
      bfrag w;
      #pragma unroll
      for (int e = 0; e < 8; ++e) w[e] = f2bf(s[e]);
      WH[q][kt] = w;
    }
    #pragma unroll
    for (int kt = 0; kt < 8; ++kt) {
      const float* s = Wih + (size_t)grow * F_ + kt * 32 + qq * 8;
      bfrag w;
      #pragma unroll
      for (int e = 0; e < 8; ++e) w[e] = f2bf(s[e]);
      WI[q][kt] = w;
    }
    bs[q] = bih[grow] + bhh[grow];
  }
  const float blc = (wv < 2) ? blin[32 * k + 16 * wv + l16] : 0.f;

  float c4[4] = {0.f, 0.f, 0.f, 0.f};
  __syncthreads();

  const int* myflags = flags + b * 16;

  for (int t = 0; t < T_; ++t) {
    f32x4 acc[4] = {{0,0,0,0},{0,0,0,0},{0,0,0,0},{0,0,0,0}};
    {
      const float* xr = x + ((size_t)(16 * b + l16) * T_ + t) * F_ + qq * 8;
      #pragma unroll
      for (int kt = 0; kt < 8; ++kt) {
        float4_t xa = *(const float4_t*)(xr + kt * 32);
        float4_t xb = *(const float4_t*)(xr + kt * 32 + 4);
        bfrag a;
        #pragma unroll
        for (int e = 0; e < 4; ++e) { a[e] = f2bf(xa[e]); a[4 + e] = f2bf(xb[e]); }
        #pragma unroll
        for (int q = 0; q < 4; ++q)
          acc[q] = __builtin_amdgcn_mfma_f32_16x16x32_bf16(a, WI[q][kt], acc[q], 0, 0, 0);
      }
    }

    if (t > 0) {
      while (true) {
        int v = gload_flag(&myflags[l & 7]);
        if (__all(v >= t)) break;
        __builtin_amdgcn_s_sleep(1);
      }
      __builtin_amdgcn_sched_barrier(0);
    }
    const int* pp = pay + (size_t)((t & 1) * GB + b) * PAYD + tid;
    int pv[16];
    #pragma unroll
    for (int j = 0; j < 16; ++j) pv[j] = gload4_cc(pp + j * 256);
    vm_drain();
    __syncthreads();

    #pragma unroll
    for (int j = 0; j < 16; ++j)
      *(int*)(smem + j * 1024 + ((tid * 4) ^ ((j & 7) << 4))) = pv[j];
    __syncthreads();

    f32x4 oacc = {blc, blc, blc, blc};
    #pragma unroll
    for (int kt = 0; kt < 16; ++kt) {
      bfrag a = *(const bfrag*)(smem + l16 * 1024 + ((kt * 64 + qq * 16) ^ swz));
      #pragma unroll
      for (int q = 0; q < 4; ++q)
        acc[q] = __builtin_amdgcn_mfma_f32_16x16x32_bf16(a, WH[q][kt], acc[q], 0, 0, 0);
      if (wv < 2) {
        bfrag wl = *(const bfrag*)(smem + 16384 + (16 * wv + l16) * 1024 +
                                   ((kt * 64 + qq * 16) ^ swz));
        oacc = __builtin_amdgcn_mfma_f32_16x16x32_bf16(a, wl, oacc, 0, 0, 0);
      }
    }

    int* ps = pay + (size_t)(((t + 1) & 1) * GB + b) * PAYD;
    #pragma unroll
    for (int r = 0; r < 4; ++r) {
      float iv = fsig(acc[0][r] + bs[0]);
      float fv = fsig(acc[1][r] + bs[1]);
      float gv = ftanh(acc[2][r] + bs[2]);
      float ov = fsig(acc[3][r] + bs[3]);
      float cn = fv * c4[r] + iv * gv;
      c4[r] = cn;
      float hn = ov * ftanh(cn);
      int hb = (int)(unsigned short)f2bf(hn);
      int pu = __shfl_xor(hb, 1);
      if ((l16 & 1) == 0) {
        int packed = (hb & 0xffff) | (pu << 16);
        gstore4_cc(ps + (m4 + r) * 256 + (32 * k + 8 * wv + (l16 >> 1)), packed);
      }
    }
    vm_drain();
    __syncthreads();
    if (tid == 0)
      gstore4_cc((void*)&flags[b * 16 + k], t + 1);

    if (t > 0 && wv < 2) {
      #pragma unroll
      for (int r = 0; r < 4; ++r)
        out[(size_t)(16 * b + m4 + r) * T_ * F_ + (size_t)(t - 1) * F_ +
            32 * k + 16 * wv + l16] = oacc[r];
    }
  }

  {
    while (true) {
      int v = gload_flag(&myflags[l & 7]);
      if (__all(v >= T_)) break;
      __builtin_amdgcn_s_sleep(1);
    }
    __builtin_amdgcn_sched_barrier(0);

    const int* pp = pay + (size_t)((T_ & 1) * GB + b) * PAYD + tid;
    int pv[16];
    #pragma unroll
    for (int j = 0; j < 16; ++j) pv[j] = gload4_cc(pp + j * 256);
    vm_drain();
    __syncthreads();
    #pragma unroll
    for (int j = 0; j < 16; ++j)
      *(int*)(smem + j * 1024 + ((tid * 4) ^ ((j & 7) << 4))) = pv[j];
    __syncthreads();

    if (wv < 2) {
      f32x4 oacc = {blc, blc, blc, blc};
      #pragma unroll
      for (int kt = 0; kt < 16; ++kt) {
        bfrag a  = *(const bfrag*)(smem + l16 * 1024 + ((kt * 64 + qq * 16) ^ swz));
        bfrag wl = *(const bfrag*)(smem + 16384 + (16 * wv + l16) * 1024 +
                                   ((kt * 64 + qq * 16) ^ swz));
        oacc = __builtin_amdgcn_mfma_f32_16x16x32_bf16(a, wl, oacc, 0, 0, 0);
      }
      #pragma unroll
      for (int r = 0; r < 4; ++r)
        out[(size_t)(16 * b + m4 + r) * T_ * F_ + (size_t)(T_ - 1) * F_ +
            32 * k + 16 * wv + l16] = oacc[r];
    }
  }
}

extern "C" void kernel_launch(void* const* d_in, const int* in_sizes, int n_in,
                              void* d_out, int out_size, void* d_ws, size_t ws_size,
                              hipStream_t stream) {
  const float* z    = (const float*)d_in[0];
  const float* x    = (const float*)d_in[1];
  const float* Wih  = (const float*)d_in[2];
  const float* Whh  = (const float*)d_in[3];
  const float* bih  = (const float*)d_in[4];
  const float* bhh  = (const float*)d_in[5];
  const float* Wlin = (const float*)d_in[6];
  const float* blin = (const float*)d_in[7];
  float* out = (float*)d_out;

  int* pay   = (int*)d_ws;                              // [0, 128K)
  int* flags = (int*)((char*)d_ws + 192 * 1024);        // [192K, +256B)
  int* rtf   = (int*)((char*)d_ws + 256 * 1024);        // [256K, +256B)

  lstm_init<<<64, 256, 0, stream>>>(z, pay, flags, rtf);
  e_rt<<<2, 64, 0, stream>>>(rtf);
  e_comp<<<NWG, 256, 0, stream>>>(Wih, Whh, bih, bhh, Wlin, blin);
  lstm_persist<<<NWG, 256, 0, stream>>>(x, Wih, Whh, bih, bhh, Wlin, blin, out,
                                        pay, flags);
}

// Round 14
// 16708.934 us; speedup vs baseline: 3.6324x; 3.6324x over previous
//
#include <hip/hip_runtime.h>
#include <hip/hip_bf16.h>

#define B_   64
#define T_   2048
#define F_   256
#define H_   512
#define GB   4                    // batch groups (16 rows each)
#define GG   8                    // gate-split WGs per group
#define NWG  (GB*GG)              // 32
#define PAYD 4096                 // payload dwords per group: 16 rows * 256 pairs

typedef __attribute__((ext_vector_type(8))) short bfrag;   // 8 bf16 (MFMA A/B)
typedef __attribute__((ext_vector_type(4))) int   int4v;
typedef __attribute__((ext_vector_type(4))) float f32x4;
typedef __attribute__((ext_vector_type(4))) float float4_t;

__device__ __forceinline__ float fsig(float x)  { return 1.0f / (1.0f + __expf(-x)); }
__device__ __forceinline__ float ftanh(float x) { return 2.0f / (1.0f + __expf(-2.0f * x)) - 1.0f; }
__device__ __forceinline__ short f2bf(float f) {
  __hip_bfloat16 h = __float2bfloat16(f);
  return __builtin_bit_cast(short, h);
}

// ---- coherence-point (sc0 sc1: bypass L1+L2, serviced at MALL) ----
__device__ __forceinline__ int gload4_cc(const void* p) {
  int r;
  asm volatile("global_load_dword %0, %1, off sc0 sc1" : "=v"(r) : "v"(p));
  return r;
}
__device__ __forceinline__ int4v gload16_cc(const void* p) {
  int4v r;
  asm volatile("global_load_dwordx4 %0, %1, off sc0 sc1" : "=v"(r) : "v"(p));
  return r;
}
__device__ __forceinline__ void gstore4_cc(void* p, int d) {
  asm volatile("global_store_dword %0, %1, off sc0 sc1" :: "v"(p), "v"(d));
}
__device__ __forceinline__ int gload_flag(const void* p) {
  int r;
  asm volatile("global_load_dword %0, %1, off sc0 sc1\n\ts_waitcnt vmcnt(0)"
               : "=v"(r) : "v"(p) : "memory");
  return r;
}
__device__ __forceinline__ void vm_drain() {
  asm volatile("s_waitcnt vmcnt(0)" ::: "memory");
  __builtin_amdgcn_sched_barrier(0);   // rule #18
}

// ---------------- init: h0 payload into buf0, flags = 0 ----------------
__global__ void lstm_init(const float* __restrict__ z, int* __restrict__ pay,
                          int* __restrict__ flags) {
  int i = blockIdx.x * blockDim.x + threadIdx.x;     // 0..16383
  if (i < GB * 16) flags[i] = 0;
  int g  = i >> 12;
  int p  = i & 4095;
  int j  = p >> 8;
  int pr = p & 255;
  int row = 16 * g + j;
  int lo = (int)((unsigned)(unsigned short)f2bf(z[(size_t)row * H_ + 2 * pr])
         | ((unsigned)(unsigned short)f2bf(z[(size_t)row * H_ + 2 * pr + 1]) << 16));
  pay[(size_t)g * PAYD + p] = lo;                    // parity-0 buffer
}

// ===== PROBE: per-wave UC instruction serialization test =====================
// Same bytes (4KB/iter), same 64B-line count (64/iter), different instr count.
// If UC VMEM instrs serialize per-wave: e_b16 ~ 4x e_b4. If equal: theory dead.
__global__ void e_b16(const int* r) {
  const int l = threadIdx.x;
  for (int it = 0; it < 4096; ++it) {
    int v[16];
    #pragma unroll
    for (int j = 0; j < 16; ++j)
      v[j] = gload4_cc(r + l + j * 64 + (it & 1) * 1024);
    vm_drain();
    #pragma unroll
    for (int j = 0; j < 16; ++j) asm volatile("" :: "v"(v[j]));   // rule #17
  }
}
__global__ void e_b4(const int* r) {
  const int l = threadIdx.x;
  for (int it = 0; it < 4096; ++it) {
    int4v v[4];
    #pragma unroll
    for (int j = 0; j < 4; ++j)
      v[j] = gload16_cc((const char*)r + l * 16 + j * 1024 + (it & 1) * 4096);
    vm_drain();
    #pragma unroll
    for (int j = 0; j < 4; ++j)
      asm volatile("" :: "v"(v[j][0]), "v"(v[j][1]), "v"(v[j][2]), "v"(v[j][3]));
  }
}

// ---------------- persistent LSTM: R9 protocol + wide payload + reorder -------
// Changes vs R9: (1) payload = 4 x dwordx4 per thread (16 -> 4 UC instrs);
// (2) flag poll FIRST, payload issued immediately, x-part computed while
// payload in flight, one drain after. Protocol/correctness identical to R9.
__global__ void __launch_bounds__(256, 1)
lstm_persist(const float* __restrict__ x,
             const float* __restrict__ Wih,  const float* __restrict__ Whh,
             const float* __restrict__ bih,  const float* __restrict__ bhh,
             const float* __restrict__ Wlin, const float* __restrict__ blin,
             float* __restrict__ out, int* __restrict__ pay,
             int* __restrict__ flags)
{
  __shared__ char smem[49152];   // [0,16K) h-tile swz | [16K,48K) W_lin slice

  const int wg  = blockIdx.x;
  const int b   = wg >> 3;
  const int k   = wg & 7;
  const int tid = threadIdx.x;
  const int wv  = tid >> 6;
  const int l   = tid & 63;
  const int l16 = l & 15;
  const int qq  = l >> 4;
  const int swz = (l16 & 7) << 4;
  const int m4  = qq << 2;

  // ---- stage W_lin slice (cols 32k..32k+32, K=512) to LDS, swizzled ----
  {
    const int oc = tid >> 3;
    const float* src = Wlin + (size_t)(32 * k + oc) * H_ + (tid & 7) * 64;
    char* dst = smem + 16384 + oc * 1024;
    #pragma unroll
    for (int i = 0; i < 8; ++i) {
      bfrag tmp;
      #pragma unroll
      for (int e = 0; e < 8; ++e) tmp[e] = f2bf(src[i * 8 + e]);
      *(int4v*)(dst + ((((tid & 7) * 128) + i * 16) ^ ((oc & 7) << 4))) =
          __builtin_bit_cast(int4v, tmp);
    }
  }

  // ---- persistent weight fragments in VGPR ----
  bfrag WH[4][16]; bfrag WI[4][8]; float bs[4];
  #pragma unroll
  for (int q = 0; q < 4; ++q) {
    const int grow = q * H_ + k * 64 + wv * 16 + l16;
    #pragma unroll
    for (int kt = 0; kt < 16; ++kt) {
      const float* s = Whh + (size_t)grow * H_ + kt * 32 + qq * 8;
      bfrag w;
      #pragma unroll
      for (int e = 0; e < 8; ++e) w[e] = f2bf(s[e]);
      WH[q][kt] = w;
    }
    #pragma unroll
    for (int kt = 0; kt < 8; ++kt) {
      const float* s = Wih + (size_t)grow * F_ + kt * 32 + qq * 8;
      bfrag w;
      #pragma unroll
      for (int e = 0; e < 8; ++e) w[e] = f2bf(s[e]);
      WI[q][kt] = w;
    }
    bs[q] = bih[grow] + bhh[grow];
  }
  const float blc = (wv < 2) ? blin[32 * k + 16 * wv + l16] : 0.f;

  float c4[4] = {0.f, 0.f, 0.f, 0.f};
  __syncthreads();

  const int* myflags = flags + b * 16;
  // payload addressing: thread tid covers row tid/16, col-pairs [(tid&15)*16,+16)
  const int prow = tid >> 4;
  const int pcol = tid & 15;

  for (int t = 0; t < T_; ++t) {
    // ---- 1: flag gate (producers set flag t at end of step t-1) ----
    if (t > 0) {
      while (true) {
        int v = gload_flag(&myflags[l & 7]);
        if (__all(v >= t)) break;
        __builtin_amdgcn_s_sleep(1);
      }
      __builtin_amdgcn_sched_barrier(0);
    }

    // ---- 2: issue payload (4 x dwordx4 = 64B/thread), then x-part on top ----
    const char* pbase = (const char*)(pay + (size_t)((t & 1) * GB + b) * PAYD) + tid * 64;
    int4v pv4[4];
    #pragma unroll
    for (int i = 0; i < 4; ++i) pv4[i] = gload16_cc(pbase + i * 16);

    f32x4 acc[4] = {{0,0,0,0},{0,0,0,0},{0,0,0,0},{0,0,0,0}};
    {
      const float* xr = x + ((size_t)(16 * b + l16) * T_ + t) * F_ + qq * 8;
      #pragma unroll
      for (int kt = 0; kt < 8; ++kt) {
        float4_t xa = *(const float4_t*)(xr + kt * 32);
        float4_t xb = *(const float4_t*)(xr + kt * 32 + 4);
        bfrag a;
        #pragma unroll
        for (int e = 0; e < 4; ++e) { a[e] = f2bf(xa[e]); a[4 + e] = f2bf(xb[e]); }
        #pragma unroll
        for (int q = 0; q < 4; ++q)
          acc[q] = __builtin_amdgcn_mfma_f32_16x16x32_bf16(a, WI[q][kt], acc[q], 0, 0, 0);
      }
    }
    vm_drain();         // payload (and x) loads complete
    __syncthreads();    // all waves done with prior iter's LDS reads

    // ---- 3: stage h-tile to LDS (swizzled, 16B chunks) ----
    {
      char* rowbase = smem + prow * 1024;
      #pragma unroll
      for (int i = 0; i < 4; ++i)
        *(int4v*)(rowbase + ((pcol * 64 + i * 16) ^ ((prow & 7) << 4))) = pv4[i];
    }
    __syncthreads();

    // ---- 4: gates h-part + fused out[t-1] ----
    f32x4 oacc = {blc, blc, blc, blc};
    #pragma unroll
    for (int kt = 0; kt < 16; ++kt) {
      bfrag a = *(const bfrag*)(smem + l16 * 1024 + ((kt * 64 + qq * 16) ^ swz));
      #pragma unroll
      for (int q = 0; q < 4; ++q)
        acc[q] = __builtin_amdgcn_mfma_f32_16x16x32_bf16(a, WH[q][kt], acc[q], 0, 0, 0);
      if (wv < 2) {
        bfrag wl = *(const bfrag*)(smem + 16384 + (16 * wv + l16) * 1024 +
                                   ((kt * 64 + qq * 16) ^ swz));
        oacc = __builtin_amdgcn_mfma_f32_16x16x32_bf16(a, wl, oacc, 0, 0, 0);
      }
    }

    // ---- 5: activations, state, payload stores -> drain -> barrier -> flag ----
    int* ps = pay + (size_t)(((t + 1) & 1) * GB + b) * PAYD;
    #pragma unroll
    for (int r = 0; r < 4; ++r) {
      float iv = fsig(acc[0][r] + bs[0]);
      float fv = fsig(acc[1][r] + bs[1]);
      float gv = ftanh(acc[2][r] + bs[2]);
      float ov = fsig(acc[3][r] + bs[3]);
      float cn = fv * c4[r] + iv * gv;
      c4[r] = cn;
      float hn = ov * ftanh(cn);
      int hb = (int)(unsigned short)f2bf(hn);
      int pu = __shfl_xor(hb, 1);
      if ((l16 & 1) == 0) {
        int packed = (hb & 0xffff) | (pu << 16);
        gstore4_cc(ps + (m4 + r) * 256 + (32 * k + 8 * wv + (l16 >> 1)), packed);
      }
    }
    vm_drain();
    __syncthreads();
    if (tid == 0)
      gstore4_cc((void*)&flags[b * 16 + k], t + 1);

    // ---- 6: out[t-1] store (cached, off critical path) ----
    if (t > 0 && wv < 2) {
      #pragma unroll
      for (int r = 0; r < 4; ++r)
        out[(size_t)(16 * b + m4 + r) * T_ * F_ + (size_t)(t - 1) * F_ +
            32 * k + 16 * wv + l16] = oacc[r];
    }
  }

  // ---- tail: out[T-1] from h_T ----
  {
    while (true) {
      int v = gload_flag(&myflags[l & 7]);
      if (__all(v >= T_)) break;
      __builtin_amdgcn_s_sleep(1);
    }
    __builtin_amdgcn_sched_barrier(0);

    const char* pbase = (const char*)(pay + (size_t)((T_ & 1) * GB + b) * PAYD) + tid * 64;
    int4v pv4[4];
    #pragma unroll
    for (int i = 0; i < 4; ++i) pv4[i] = gload16_cc(pbase + i * 16);
    vm_drain();
    __syncthreads();
    {
      char* rowbase = smem + prow * 1024;
      #pragma unroll
      for (int i = 0; i < 4; ++i)
        *(int4v*)(rowbase + ((pcol * 64 + i * 16) ^ ((prow & 7) << 4))) = pv4[i];
    }
    __syncthreads();

    if (wv < 2) {
      f32x4 oacc = {blc, blc, blc, blc};
      #pragma unroll
      for (int kt = 0; kt < 16; ++kt) {
        bfrag a  = *(const bfrag*)(smem + l16 * 1024 + ((kt * 64 + qq * 16) ^ swz));
        bfrag wl = *(const bfrag*)(smem + 16384 + (16 * wv + l16) * 1024 +
                                   ((kt * 64 + qq * 16) ^ swz));
        oacc = __builtin_amdgcn_mfma_f32_16x16x32_bf16(a, wl, oacc, 0, 0, 0);
      }
      #pragma unroll
      for (int r = 0; r < 4; ++r)
        out[(size_t)(16 * b + m4 + r) * T_ * F_ + (size_t)(T_ - 1) * F_ +
            32 * k + 16 * wv + l16] = oacc[r];
    }
  }
}

extern "C" void kernel_launch(void* const* d_in, const int* in_sizes, int n_in,
                              void* d_out, int out_size, void* d_ws, size_t ws_size,
                              hipStream_t stream) {
  const float* z    = (const float*)d_in[0];
  const float* x    = (const float*)d_in[1];
  const float* Wih  = (const float*)d_in[2];
  const float* Whh  = (const float*)d_in[3];
  const float* bih  = (const float*)d_in[4];
  const float* bhh  = (const float*)d_in[5];
  const float* Wlin = (const float*)d_in[6];
  const float* blin = (const float*)d_in[7];
  float* out = (float*)d_out;

  int* pay   = (int*)d_ws;                              // [0, 128K)
  int* flags = (int*)((char*)d_ws + 192 * 1024);        // [192K, +256B)
  int* preg  = (int*)((char*)d_ws + 256 * 1024);        // [256K, +32K) probe region

  lstm_init<<<64, 256, 0, stream>>>(z, pay, flags);
  e_b16<<<1, 64, 0, stream>>>(preg);
  e_b4 <<<1, 64, 0, stream>>>(preg);
  lstm_persist<<<NWG, 256, 0, stream>>>(x, Wih, Whh, bih, bhh, Wlin, blin, out,
                                        pay, flags);
}

// Round 15
// 14236.877 us; speedup vs baseline: 4.2631x; 1.1736x over previous
//
#include <hip/hip_runtime.h>
#include <hip/hip_bf16.h>

#define B_   64
#define T_   2048
#define F_   256
#define H_   512
#define GB   4                    // batch groups (16 rows each)
#define GG   8                    // gate-split WGs per group
#define NWG  (GB*GG)              // 32
#define PAYD 4096                 // payload dwords per group (column-major: pair*16+row)

typedef __attribute__((ext_vector_type(8))) short bfrag;   // 8 bf16 (MFMA A/B)
typedef __attribute__((ext_vector_type(4))) int   int4v;
typedef __attribute__((ext_vector_type(4))) float f32x4;
typedef __attribute__((ext_vector_type(4))) float float4_t;

__device__ __forceinline__ float fsig(float x)  { return 1.0f / (1.0f + __expf(-x)); }
__device__ __forceinline__ float ftanh(float x) { return 2.0f / (1.0f + __expf(-2.0f * x)) - 1.0f; }
__device__ __forceinline__ short f2bf(float f) {
  __hip_bfloat16 h = __float2bfloat16(f);
  return __builtin_bit_cast(short, h);
}

// ---- coherence-point (sc0 sc1: bypass L1+L2, serviced at MALL) ----
__device__ __forceinline__ int4v gload16_cc(const void* p) {
  int4v r;
  asm volatile("global_load_dwordx4 %0, %1, off sc0 sc1" : "=v"(r) : "v"(p));
  return r;
}
__device__ __forceinline__ void gstore16_cc(void* p, int4v d) {
  asm volatile("global_store_dwordx4 %0, %1, off sc0 sc1" :: "v"(p), "v"(d));
}
__device__ __forceinline__ void gstore4_cc(void* p, int d) {
  asm volatile("global_store_dword %0, %1, off sc0 sc1" :: "v"(p), "v"(d));
}
__device__ __forceinline__ int gload_flag(const void* p) {
  int r;
  asm volatile("global_load_dword %0, %1, off sc0 sc1\n\ts_waitcnt vmcnt(0)"
               : "=v"(r) : "v"(p) : "memory");
  return r;
}
__device__ __forceinline__ void vm_drain() {
  asm volatile("s_waitcnt vmcnt(0)" ::: "memory");
  __builtin_amdgcn_sched_barrier(0);   // rule #18
}

// ---------------- init: h0 payload (column-major) into buf0, flags = 0 --------
__global__ void lstm_init(const float* __restrict__ z, int* __restrict__ pay,
                          int* __restrict__ flags) {
  int i = blockIdx.x * blockDim.x + threadIdx.x;     // 0..16383
  if (i < GB * 32) flags[i] = 0;                     // 32 per-wave flags per group
  int g  = i >> 12;
  int p  = i & 4095;
  int P  = p >> 4;             // col pair 0..255
  int j  = p & 15;             // row within group
  int row = 16 * g + j;
  int lo = (int)((unsigned)(unsigned short)f2bf(z[(size_t)row * H_ + 2 * P])
         | ((unsigned)(unsigned short)f2bf(z[(size_t)row * H_ + 2 * P + 1]) << 16));
  pay[(size_t)g * PAYD + P * 16 + j] = lo;           // parity-0, column-major
}

// ---------------- persistent LSTM: R9 protocol, harvested critical path -------
// vs R9: (1) column-major payload -> producer 1 dwordx4/lane, consumer 4
// dwordx4/thread, staging = R9's conflict-free dword pattern; (2) per-wave
// flags (no producer barrier, no max-over-waves before flag); (3) out-GEMM
// unfused, after flag store; (4) payload issued before x-part, one drain.
__global__ void __launch_bounds__(256, 1)
lstm_persist(const float* __restrict__ x,
             const float* __restrict__ Wih,  const float* __restrict__ Whh,
             const float* __restrict__ bih,  const float* __restrict__ bhh,
             const float* __restrict__ Wlin, const float* __restrict__ blin,
             float* __restrict__ out, int* __restrict__ pay,
             int* __restrict__ flags)
{
  __shared__ char smem[49152];   // [0,16K) h-tile swz | [16K,48K) W_lin slice

  const int wg  = blockIdx.x;
  const int b   = wg >> 3;
  const int k   = wg & 7;
  const int tid = threadIdx.x;
  const int wv  = tid >> 6;
  const int l   = tid & 63;
  const int l16 = l & 15;
  const int qq  = l >> 4;
  const int swz = (l16 & 7) << 4;
  const int m4  = qq << 2;

  // ---- stage W_lin slice (cols 32k..32k+32, K=512) to LDS, swizzled ----
  {
    const int oc = tid >> 3;
    const float* src = Wlin + (size_t)(32 * k + oc) * H_ + (tid & 7) * 64;
    char* dst = smem + 16384 + oc * 1024;
    #pragma unroll
    for (int i = 0; i < 8; ++i) {
      bfrag tmp;
      #pragma unroll
      for (int e = 0; e < 8; ++e) tmp[e] = f2bf(src[i * 8 + e]);
      *(int4v*)(dst + ((((tid & 7) * 128) + i * 16) ^ ((oc & 7) << 4))) =
          __builtin_bit_cast(int4v, tmp);
    }
  }

  // ---- persistent weight fragments in VGPR ----
  bfrag WH[4][16]; bfrag WI[4][8]; float bs[4];
  #pragma unroll
  for (int q = 0; q < 4; ++q) {
    const int grow = q * H_ + k * 64 + wv * 16 + l16;
    #pragma unroll
    for (int kt = 0; kt < 16; ++kt) {
      const float* s = Whh + (size_t)grow * H_ + kt * 32 + qq * 8;
      bfrag w;
      #pragma unroll
      for (int e = 0; e < 8; ++e) w[e] = f2bf(s[e]);
      WH[q][kt] = w;
    }
    #pragma unroll
    for (int kt = 0; kt < 8; ++kt) {
      const float* s = Wih + (size_t)grow * F_ + kt * 32 + qq * 8;
      bfrag w;
      #pragma unroll
      for (int e = 0; e < 8; ++e) w[e] = f2bf(s[e]);
      WI[q][kt] = w;
    }
    bs[q] = bih[grow] + bhh[grow];
  }
  const float blc = (wv < 2) ? blin[32 * k + 16 * wv + l16] : 0.f;

  float c4[4] = {0.f, 0.f, 0.f, 0.f};
  __syncthreads();

  const int* myflags = flags + b * 32;               // 32 per-wave flags (1 line pair)
  const int  myPair  = 32 * k + 8 * wv + (l16 >> 1); // producer pair (even lanes)

  for (int t = 0; t < T_; ++t) {
    // ---- 1: gate on 32 per-wave flags (lanes 0..31 poll one each) ----
    if (t > 0) {
      while (true) {
        int v = (l < 32) ? gload_flag(&myflags[l]) : t;
        if (__all(v >= t)) break;
        __builtin_amdgcn_s_sleep(1);
      }
      __builtin_amdgcn_sched_barrier(0);
    }

    // ---- 2: issue payload (4 x dwordx4, thread = pair tid, rows 0..15),
    //         then x-part on top (loads in flight) ----
    const char* pbase = (const char*)(pay + (size_t)((t & 1) * GB + b) * PAYD) + tid * 64;
    int4v pv4[4];
    #pragma unroll
    for (int a = 0; a < 4; ++a) pv4[a] = gload16_cc(pbase + a * 16);

    f32x4 acc[4] = {{0,0,0,0},{0,0,0,0},{0,0,0,0},{0,0,0,0}};
    {
      const float* xr = x + ((size_t)(16 * b + l16) * T_ + t) * F_ + qq * 8;
      #pragma unroll
      for (int kt = 0; kt < 8; ++kt) {
        float4_t xa = *(const float4_t*)(xr + kt * 32);
        float4_t xb = *(const float4_t*)(xr + kt * 32 + 4);
        bfrag a;
        #pragma unroll
        for (int e = 0; e < 4; ++e) { a[e] = f2bf(xa[e]); a[4 + e] = f2bf(xb[e]); }
        #pragma unroll
        for (int q = 0; q < 4; ++q)
          acc[q] = __builtin_amdgcn_mfma_f32_16x16x32_bf16(a, WI[q][kt], acc[q], 0, 0, 0);
      }
    }
    vm_drain();
    __syncthreads();   // prior iter's LDS readers (out-GEMM) done

    // ---- 3: stage h-tile (thread tid = pair column, row j = 4a+i) ----
    #pragma unroll
    for (int a = 0; a < 4; ++a) {
      #pragma unroll
      for (int i = 0; i < 4; ++i) {
        const int j = 4 * a + i;
        *(int*)(smem + j * 1024 + ((tid * 4) ^ ((j & 7) << 4))) = pv4[a][i];
      }
    }
    __syncthreads();

    // ---- 4: gates h-part (pure, all waves symmetric: 64 MFMA) ----
    #pragma unroll
    for (int kt = 0; kt < 16; ++kt) {
      bfrag a = *(const bfrag*)(smem + l16 * 1024 + ((kt * 64 + qq * 16) ^ swz));
      #pragma unroll
      for (int q = 0; q < 4; ++q)
        acc[q] = __builtin_amdgcn_mfma_f32_16x16x32_bf16(a, WH[q][kt], acc[q], 0, 0, 0);
    }

    // ---- 5: activations, state, ONE dwordx4 payload store per even lane ----
    int* ps = pay + (size_t)(((t + 1) & 1) * GB + b) * PAYD;
    int hb[4];
    #pragma unroll
    for (int r = 0; r < 4; ++r) {
      float iv = fsig(acc[0][r] + bs[0]);
      float fv = fsig(acc[1][r] + bs[1]);
      float gv = ftanh(acc[2][r] + bs[2]);
      float ov = fsig(acc[3][r] + bs[3]);
      float cn = fv * c4[r] + iv * gv;
      c4[r] = cn;
      hb[r] = (int)(unsigned short)f2bf(ov * ftanh(cn));
    }
    {
      int4v pk;
      #pragma unroll
      for (int r = 0; r < 4; ++r) {
        int pu = __shfl_xor(hb[r], 1);
        pk[r] = (hb[r] & 0xffff) | (pu << 16);
      }
      if ((l16 & 1) == 0)
        gstore16_cc(ps + myPair * 16 + m4, pk);
    }
    vm_drain();                           // this wave's stores at coherence point
    if (l == 0)
      gstore4_cc((void*)&flags[b * 32 + k * 4 + wv], t + 1);   // per-wave flag

    // ---- 6: out[t-1] GEMM + store (off inter-WG critical path) ----
    if (wv < 2) {
      f32x4 oacc = {blc, blc, blc, blc};
      #pragma unroll
      for (int kt = 0; kt < 16; ++kt) {
        bfrag a  = *(const bfrag*)(smem + l16 * 1024 + ((kt * 64 + qq * 16) ^ swz));
        bfrag wl = *(const bfrag*)(smem + 16384 + (16 * wv + l16) * 1024 +
                                   ((kt * 64 + qq * 16) ^ swz));
        oacc = __builtin_amdgcn_mfma_f32_16x16x32_bf16(a, wl, oacc, 0, 0, 0);
      }
      if (t > 0) {
        #pragma unroll
        for (int r = 0; r < 4; ++r)
          out[(size_t)(16 * b + m4 + r) * T_ * F_ + (size_t)(t - 1) * F_ +
              32 * k + 16 * wv + l16] = oacc[r];
      }
    }
  }

  // ---- tail: out[T-1] from h_T (parity 0, flags >= T_) ----
  {
    while (true) {
      int v = (l < 32) ? gload_flag(&myflags[l]) : T_;
      if (__all(v >= T_)) break;
      __builtin_amdgcn_s_sleep(1);
    }
    __builtin_amdgcn_sched_barrier(0);

    const char* pbase = (const char*)(pay + (size_t)((T_ & 1) * GB + b) * PAYD) + tid * 64;
    int4v pv4[4];
    #pragma unroll
    for (int a = 0; a < 4; ++a) pv4[a] = gload16_cc(pbase + a * 16);
    vm_drain();
    __syncthreads();
    #pragma unroll
    for (int a = 0; a < 4; ++a) {
      #pragma unroll
      for (int i = 0; i < 4; ++i) {
        const int j = 4 * a + i;
        *(int*)(smem + j * 1024 + ((tid * 4) ^ ((j & 7) << 4))) = pv4[a][i];
      }
    }
    __syncthreads();

    if (wv < 2) {
      f32x4 oacc = {blc, blc, blc, blc};
      #pragma unroll
      for (int kt = 0; kt < 16; ++kt) {
        bfrag a  = *(const bfrag*)(smem + l16 * 1024 + ((kt * 64 + qq * 16) ^ swz));
        bfrag wl = *(const bfrag*)(smem + 16384 + (16 * wv + l16) * 1024 +
                                   ((kt * 64 + qq * 16) ^ swz));
        oacc = __builtin_amdgcn_mfma_f32_16x16x32_bf16(a, wl, oacc, 0, 0, 0);
      }
      #pragma unroll
      for (int r = 0; r < 4; ++r)
        out[(size_t)(16 * b + m4 + r) * T_ * F_ + (size_t)(T_ - 1) * F_ +
            32 * k + 16 * wv + l16] = oacc[r];
    }
  }
}

extern "C" void kernel_launch(void* const* d_in, const int* in_sizes, int n_in,
                              void* d_out, int out_size, void* d_ws, size_t ws_size,
                              hipStream_t stream) {
  const float* z    = (const float*)d_in[0];
  const float* x    = (const float*)d_in[1];
  const float* Wih  = (const float*)d_in[2];
  const float* Whh  = (const float*)d_in[3];
  const float* bih  = (const float*)d_in[4];
  const float* bhh  = (const float*)d_in[5];
  const float* Wlin = (const float*)d_in[6];
  const float* blin = (const float*)d_in[7];
  float* out = (float*)d_out;

  int* pay   = (int*)d_ws;                              // [0, 128K) 2-parity payload
  int* flags = (int*)((char*)d_ws + 192 * 1024);        // [192K, +512B) 128 flags

  lstm_init<<<64, 256, 0, stream>>>(z, pay, flags);
  lstm_persist<<<NWG, 256, 0, stream>>>(x, Wih, Whh, bih, bhh, Wlin, blin, out,
                                        pay, flags);
}